// Round 1
// baseline (454.421 us; speedup 1.0000x reference)
//
#include <hip/hip_runtime.h>

#define B 256
#define R 2048
#define H 64
#define E 20
#define LN_EPS 1e-5f

typedef float f32x4 __attribute__((ext_vector_type(4)));
typedef short s16x8 __attribute__((ext_vector_type(8)));

__device__ __forceinline__ unsigned short f2bf(float x){
  unsigned int u = __float_as_uint(x);
  u += 0x7fffu + ((u >> 16) & 1u);   // round-to-nearest-even
  return (unsigned short)(u >> 16);
}

__device__ __forceinline__ float wave64_sum(float v){
  #pragma unroll
  for (int m = 1; m < 64; m <<= 1) v += __shfl_xor(v, m, 64);
  return v;
}

// ---------------------------------------------------------------------------
// prep: prompt_zero = LN(upd_b); c1z = prompt_zero@W1_bot + fus_b1;
//       gz = prompt_zero . gateW_bot + gate_b; bf16-transposed W1_top, W2.
// ---------------------------------------------------------------------------
__global__ __launch_bounds__(256) void prep_kernel(
    const float* __restrict__ upd_b, const float* __restrict__ ln_g,
    const float* __restrict__ ln_b,  const float* __restrict__ fus_W1,
    const float* __restrict__ fus_b1,const float* __restrict__ fus_W2,
    const float* __restrict__ gate_W,const float* __restrict__ gate_b,
    unsigned short* __restrict__ w1t, unsigned short* __restrict__ w2t,
    float* __restrict__ c1z, float* __restrict__ gz)
{
  __shared__ float pz[H];
  int t = threadIdx.x;
  if (t < H){
    float u  = upd_b[t];
    float mu = wave64_sum(u) * (1.0f/H);
    float d  = u - mu;
    float var= wave64_sum(d*d) * (1.0f/H);
    float p  = d * rsqrtf(var + LN_EPS) * ln_g[t] + ln_b[t];
    pz[t] = p;
  }
  __syncthreads();
  if (t < H){
    float acc = fus_b1[t];
    #pragma unroll 8
    for (int k = 0; k < H; k++) acc += pz[k] * fus_W1[(H+k)*H + t];
    c1z[t] = acc;
  } else if (t >= 64 && t < 128){
    int l = t - 64;
    float part = pz[l] * gate_W[H + l];
    part = wave64_sum(part);
    if (l == 0) gz[0] = part + gate_b[0];
  }
  // transposed bf16 weights: w1t[n*H+k] = W1_top[k][n], w2t[n*H+k] = W2[k][n]
  for (int i = t; i < H*H; i += 256){
    int n = i >> 6, k = i & 63;
    w1t[i] = f2bf(fus_W1[k*H + n]);
    w2t[i] = f2bf(fus_W2[k*H + n]);
  }
}

// ---------------------------------------------------------------------------
// edge: per-sample prompt encoder for the <=E touched rows (sparse output).
// ---------------------------------------------------------------------------
__global__ __launch_bounds__(64) void edge_kernel(
    const int* __restrict__ qrel, const int* __restrict__ etype,
    const float* __restrict__ noise,
    const float* __restrict__ msg_W, const float* __restrict__ msg_b,
    const float* __restrict__ upd_W, const float* __restrict__ upd_b,
    const float* __restrict__ ln_g,  const float* __restrict__ ln_b,
    int* __restrict__ trows, float* __restrict__ tprompt)
{
  __shared__ float wsum[H*H];      // msg_W top + bottom halves
  __shared__ float uW[H*H];
  __shared__ float hbuf[H];
  __shared__ float msgbuf[E][H];
  __shared__ float aggbuf[H];
  __shared__ int   et[E];

  int b = blockIdx.x, t = threadIdx.x;
  if (t < E) et[t] = etype[b*E + t];
  int q = qrel[b];
  for (int k = 0; k < H; k++){
    wsum[k*H + t] = msg_W[k*H + t] + msg_W[(H+k)*H + t];
    uW[k*H + t]   = upd_W[k*H + t];
  }
  __syncthreads();

  for (int e = 0; e < E; e++){
    int r = et[e];
    float hv = (r == q) ? 1.0f : noise[(b*R + r)*H + t] * 0.1f;
    hbuf[t] = hv;
    __syncthreads();
    float acc = msg_b[t];
    #pragma unroll 8
    for (int k = 0; k < H; k++) acc += hbuf[k] * wsum[k*H + t];
    msgbuf[e][t] = fmaxf(acc, 0.f);
    __syncthreads();
  }

  for (int e = 0; e < E; e++){
    int r = et[e];
    bool first = true;
    for (int e2 = 0; e2 < e; e2++) if (et[e2] == r) first = false;
    if (!first){ if (t == 0) trows[b*E + e] = -1; continue; }
    float agg = 0.f;
    for (int e2 = e; e2 < E; e2++) if (et[e2] == r) agg += msgbuf[e2][t];
    aggbuf[t] = agg;
    __syncthreads();
    float u = upd_b[t];
    #pragma unroll 8
    for (int k = 0; k < H; k++) u += aggbuf[k] * uW[k*H + t];
    float mu = wave64_sum(u) * (1.0f/H);
    float d  = u - mu;
    float var= wave64_sum(d*d) * (1.0f/H);
    float p  = d * rsqrtf(var + LN_EPS) * ln_g[t] + ln_b[t];
    tprompt[(b*E + e)*H + t] = p;
    if (t == 0) trows[b*E + e] = r;
    __syncthreads();
  }
}

// ---------------------------------------------------------------------------
// main: dense per-row path with prompt == prompt_zero folded into c1z/gz.
// One wave = 16 rows; MFMA 16x16x32 bf16, f32 accum; LDS round-trip for
// hidden (C-layout -> A-layout).
// ---------------------------------------------------------------------------
__global__ __launch_bounds__(256) void main_kernel(
    const float* __restrict__ base,
    const float* __restrict__ gate_W,
    const unsigned short* __restrict__ w1t,
    const unsigned short* __restrict__ w2t,
    const float* __restrict__ c1z,
    const float* __restrict__ fus_b2,
    const float* __restrict__ gz_p,
    float* __restrict__ out)
{
  __shared__ unsigned short lw1[H*72];       // [n][k], padded stride 72
  __shared__ unsigned short lw2[H*72];
  __shared__ unsigned short lhid[4][16*72];  // per-wave hidden tile
  __shared__ float lg[4][16];
  __shared__ float lc1[H];
  __shared__ float lb2[H];
  __shared__ float lgw[H];

  int tid = threadIdx.x;
  const unsigned int* w1u = (const unsigned int*)w1t;
  const unsigned int* w2u = (const unsigned int*)w2t;
  for (int i = tid; i < H*H/2; i += 256){
    int n = i >> 5, kk = (i & 31) * 2;
    *(unsigned int*)&lw1[n*72 + kk] = w1u[i];
    *(unsigned int*)&lw2[n*72 + kk] = w2u[i];
  }
  if (tid < H){ lc1[tid] = c1z[tid]; lb2[tid] = fus_b2[tid]; lgw[tid] = gate_W[tid]; }
  __syncthreads();

  int w = tid >> 6, ln = tid & 63;
  int m = ln & 15, q = ln >> 4;
  int rowbase = blockIdx.x * 64 + w * 16;
  const float* arow = base + (rowbase + m) * H;

  f32x4 a0 = *(const f32x4*)(arow + q*8);
  f32x4 a1 = *(const f32x4*)(arow + q*8 + 4);
  f32x4 a2 = *(const f32x4*)(arow + 32 + q*8);
  f32x4 a3 = *(const f32x4*)(arow + 32 + q*8 + 4);

  // gate logit partial: base . gate_W[0:64]  (f32)
  float gp = 0.f;
  #pragma unroll
  for (int j = 0; j < 4; j++){
    gp += a0[j]*lgw[q*8+j]    + a1[j]*lgw[q*8+4+j];
    gp += a2[j]*lgw[32+q*8+j] + a3[j]*lgw[32+q*8+4+j];
  }
  gp += __shfl_xor(gp, 16, 64);
  gp += __shfl_xor(gp, 32, 64);
  float g = 1.0f / (1.0f + __expf(-(gp + gz_p[0])));
  if (q == 0) lg[w][m] = g;

  // A-frags (lane: row m = ln&15, k = q*8+j)
  s16x8 A0, A1;
  #pragma unroll
  for (int j = 0; j < 4; j++){
    A0[j]   = (short)f2bf(a0[j]);
    A0[j+4] = (short)f2bf(a1[j]);
    A1[j]   = (short)f2bf(a2[j]);
    A1[j+4] = (short)f2bf(a3[j]);
  }

  // hidden = relu(base @ W1_top + c1z)
  f32x4 hacc[4];
  #pragma unroll
  for (int ct = 0; ct < 4; ct++){
    const s16x8 B0 = *(const s16x8*)&lw1[(ct*16 + m)*72 + q*8];
    const s16x8 B1 = *(const s16x8*)&lw1[(ct*16 + m)*72 + 32 + q*8];
    f32x4 z = {0.f, 0.f, 0.f, 0.f};
    f32x4 c = __builtin_amdgcn_mfma_f32_16x16x32_bf16(A0, B0, z, 0, 0, 0);
    hacc[ct] = __builtin_amdgcn_mfma_f32_16x16x32_bf16(A1, B1, c, 0, 0, 0);
  }
  // D layout: col = ln&15 (+16*ct), row = q*4 + reg  -> write bf16 to LDS
  #pragma unroll
  for (int ct = 0; ct < 4; ct++){
    float c1v = lc1[ct*16 + m];
    #pragma unroll
    for (int r = 0; r < 4; r++){
      float v = fmaxf(hacc[ct][r] + c1v, 0.f);
      lhid[w][(q*4 + r)*72 + ct*16 + m] = f2bf(v);
    }
  }
  __syncthreads();

  // fused = hidden @ W2 + fus_b2
  s16x8 HA0 = *(const s16x8*)&lhid[w][m*72 + q*8];
  s16x8 HA1 = *(const s16x8*)&lhid[w][m*72 + 32 + q*8];
  f32x4 facc[4];
  #pragma unroll
  for (int ct = 0; ct < 4; ct++){
    const s16x8 B0 = *(const s16x8*)&lw2[(ct*16 + m)*72 + q*8];
    const s16x8 B1 = *(const s16x8*)&lw2[(ct*16 + m)*72 + 32 + q*8];
    f32x4 z = {0.f, 0.f, 0.f, 0.f};
    f32x4 c = __builtin_amdgcn_mfma_f32_16x16x32_bf16(HA0, B0, z, 0, 0, 0);
    facc[ct] = __builtin_amdgcn_mfma_f32_16x16x32_bf16(HA1, B1, c, 0, 0, 0);
  }

  float gv[4];
  #pragma unroll
  for (int r = 0; r < 4; r++) gv[r] = lg[w][q*4 + r];

  #pragma unroll
  for (int ct = 0; ct < 4; ct++){
    int col = ct*16 + m;
    float b2v = lb2[col];
    #pragma unroll
    for (int r = 0; r < 4; r++){
      int row = rowbase + q*4 + r;
      float bval = base[row*H + col];
      float f = facc[ct][r] + b2v;
      out[row*H + col] = fmaf(gv[r], f - bval, bval);  // g*f + (1-g)*b
    }
  }
}

// ---------------------------------------------------------------------------
// fixup: recompute the <=20 touched rows per sample with their true prompt.
// ---------------------------------------------------------------------------
__global__ __launch_bounds__(64) void fixup_kernel(
    const float* __restrict__ base,
    const float* __restrict__ fus_W1, const float* __restrict__ fus_b1,
    const float* __restrict__ fus_W2, const float* __restrict__ fus_b2,
    const float* __restrict__ gate_W, const float* __restrict__ gate_b,
    const int* __restrict__ trows, const float* __restrict__ tprompt,
    float* __restrict__ out)
{
  __shared__ float bl[H], pl[H], hl[H];
  int b = blockIdx.x, t = threadIdx.x;
  for (int e = 0; e < E; e++){
    int r = trows[b*E + e];
    if (r < 0) continue;   // uniform across block
    float bv = base[(b*R + r)*H + t];
    float pv = tprompt[(b*E + e)*H + t];
    bl[t] = bv; pl[t] = pv;
    __syncthreads();
    float acc = fus_b1[t];
    #pragma unroll 8
    for (int k = 0; k < H; k++)
      acc += bl[k]*fus_W1[k*H + t] + pl[k]*fus_W1[(H+k)*H + t];
    float h = fmaxf(acc, 0.f);
    hl[t] = h;
    __syncthreads();
    float f = fus_b2[t];
    #pragma unroll 8
    for (int k = 0; k < H; k++) f += hl[k]*fus_W2[k*H + t];
    float gp = bv*gate_W[t] + pv*gate_W[H + t];
    gp = wave64_sum(gp);
    float g = 1.0f/(1.0f + __expf(-(gp + gate_b[0])));
    out[(b*R + r)*H + t] = fmaf(g, f - bv, bv);
    __syncthreads();
  }
}

// ---------------------------------------------------------------------------
extern "C" void kernel_launch(void* const* d_in, const int* in_sizes, int n_in,
                              void* d_out, int out_size, void* d_ws, size_t ws_size,
                              hipStream_t stream)
{
  const int*   qrel   = (const int*)d_in[0];
  const int*   etyp   = (const int*)d_in[1];
  const float* base   = (const float*)d_in[2];
  const float* noise  = (const float*)d_in[3];
  const float* msg_W  = (const float*)d_in[4];
  const float* msg_b  = (const float*)d_in[5];
  const float* upd_W  = (const float*)d_in[6];
  const float* upd_b  = (const float*)d_in[7];
  const float* ln_g   = (const float*)d_in[8];
  const float* ln_b   = (const float*)d_in[9];
  const float* fus_W1 = (const float*)d_in[10];
  const float* fus_b1 = (const float*)d_in[11];
  const float* fus_W2 = (const float*)d_in[12];
  const float* fus_b2 = (const float*)d_in[13];
  const float* gate_W = (const float*)d_in[14];
  const float* gate_b = (const float*)d_in[15];
  float* out = (float*)d_out;

  char* ws = (char*)d_ws;
  float* tprompt = (float*)ws;                                   // B*E*H f32
  int*   trows   = (int*)(ws + (size_t)B*E*H*4);                 // B*E int
  unsigned short* w1t = (unsigned short*)(ws + (size_t)B*E*H*4 + (size_t)B*E*4);
  unsigned short* w2t = w1t + H*H;
  float* c1z = (float*)(w2t + H*H);
  float* gz  = c1z + H;

  prep_kernel<<<1, 256, 0, stream>>>(upd_b, ln_g, ln_b, fus_W1, fus_b1,
                                     fus_W2, gate_W, gate_b, w1t, w2t, c1z, gz);
  edge_kernel<<<B, 64, 0, stream>>>(qrel, etyp, noise, msg_W, msg_b,
                                    upd_W, upd_b, ln_g, ln_b, trows, tprompt);
  main_kernel<<<(B*R)/64, 256, 0, stream>>>(base, gate_W, w1t, w2t, c1z,
                                            fus_b2, gz, out);
  fixup_kernel<<<B, 64, 0, stream>>>(base, fus_W1, fus_b1, fus_W2, fus_b2,
                                     gate_W, gate_b, trows, tprompt, out);
}

// Round 2
// 359.000 us; speedup vs baseline: 1.2658x; 1.2658x over previous
//
#include <hip/hip_runtime.h>

#define B 256
#define R 2048
#define H 64
#define E 20
#define LN_EPS 1e-5f

#define NB_EDGE 256
#define NB_MAIN 2048
#define TILES_PER_BLOCK 4   // NB_MAIN * TILES_PER_BLOCK * 64 == B*R

typedef float f32x4 __attribute__((ext_vector_type(4)));
typedef short s16x8 __attribute__((ext_vector_type(8)));

__device__ __forceinline__ unsigned short f2bf(float x){
  unsigned int u = __float_as_uint(x);
  u += 0x7fffu + ((u >> 16) & 1u);   // round-to-nearest-even
  return (unsigned short)(u >> 16);
}

__device__ __forceinline__ float wave64_sum(float v){
  #pragma unroll
  for (int m = 1; m < 64; m <<= 1) v += __shfl_xor(v, m, 64);
  return v;
}

// ---------------------------------------------------------------------------
// LDS layouts (union: edge blocks vs main blocks)
// ---------------------------------------------------------------------------
struct MainS {
  unsigned short lw1[H*72];        // W1_top transposed [n][k], bf16, pad 72
  unsigned short lw2[H*72];        // W2 transposed    [n][k], bf16, pad 72
  unsigned short lhid[4][16*72];   // per-wave hidden tile (bf16)
  float lg[4][16];                 // per-wave gate values
  float lc1[H];                    // prompt_zero @ W1_bot + fus_b1
  float lb2[H];
  float lgw[H];                    // gate_W top half
  float lgz;                       // prompt_zero . gate_W_bot + gate_b
};
struct EdgeS {
  float wsum[H*H];                 // msg_W top + bottom halves
  float msgbuf[E][H];
  int   et[E];
};
union SMem { MainS m; EdgeS e; };

// ---------------------------------------------------------------------------
// fused kernel: blocks [0,NB_EDGE) = per-sample prompt encoder (sparse rows),
//               blocks [NB_EDGE, NB_EDGE+NB_MAIN) = dense main path.
// ---------------------------------------------------------------------------
__global__ __launch_bounds__(256) void fused_kernel(
    const int* __restrict__ qrel, const int* __restrict__ etype,
    const float* __restrict__ base, const float* __restrict__ noise,
    const float* __restrict__ msg_W, const float* __restrict__ msg_b,
    const float* __restrict__ upd_W, const float* __restrict__ upd_b,
    const float* __restrict__ ln_g,  const float* __restrict__ ln_b,
    const float* __restrict__ fus_W1,const float* __restrict__ fus_b1,
    const float* __restrict__ fus_W2,const float* __restrict__ fus_b2,
    const float* __restrict__ gate_W,const float* __restrict__ gate_b,
    int* __restrict__ trows, float* __restrict__ tprompt,
    float* __restrict__ out)
{
  __shared__ SMem smem;
  int tid = threadIdx.x;
  int w = tid >> 6, ln = tid & 63;

  if (blockIdx.x < NB_EDGE) {
    // ------------------------------ EDGE PATH ------------------------------
    EdgeS* S = &smem.e;
    int b = blockIdx.x;
    if (tid < E) S->et[tid] = etype[b*E + tid];
    for (int i = tid; i < H*H; i += 256)
      S->wsum[i] = msg_W[i] + msg_W[H*H + i];
    __syncthreads();
    int q = qrel[b];

    // phase B: messages (wave w handles e = w, w+4, ...)
    #pragma unroll
    for (int i = 0; i < E/4; ++i) {
      int e = w + i*4;
      int r = S->et[e];
      float hv = (r == q) ? 1.0f : noise[((size_t)b*R + r)*H + ln] * 0.1f;
      float acc = msg_b[ln];
      #pragma unroll 8
      for (int k = 0; k < H; ++k)
        acc += __shfl(hv, k, 64) * S->wsum[k*H + ln];
      S->msgbuf[e][ln] = fmaxf(acc, 0.f);
    }
    __syncthreads();

    // phase C: dedup + aggregate + update-net + LN
    #pragma unroll
    for (int i = 0; i < E/4; ++i) {
      int e = w + i*4;
      int r = S->et[e];
      bool first = true;
      for (int e2 = 0; e2 < e; ++e2) if (S->et[e2] == r) first = false;
      if (!first) { if (ln == 0) trows[b*E + e] = -1; continue; }
      float agg = 0.f;
      for (int e2 = e; e2 < E; ++e2)
        if (S->et[e2] == r) agg += S->msgbuf[e2][ln];
      float u = upd_b[ln];
      #pragma unroll 8
      for (int k = 0; k < H; ++k)
        u += __shfl(agg, k, 64) * upd_W[k*H + ln];
      float mu = wave64_sum(u) * (1.0f/H);
      float d  = u - mu;
      float var= wave64_sum(d*d) * (1.0f/H);
      float p  = d * rsqrtf(var + LN_EPS) * ln_g[ln] + ln_b[ln];
      tprompt[(b*E + e)*H + ln] = p;
      if (ln == 0) trows[b*E + e] = r;
    }
    return;
  }

  // ------------------------------- MAIN PATH -------------------------------
  MainS* S = &smem.m;
  // stage: coalesced global read, transposed bf16 LDS write
  for (int i = tid; i < H*H; i += 256) {
    int k = i >> 6, n = i & 63;
    S->lw1[n*72 + k] = f2bf(fus_W1[i]);   // top half of fus_W1
    S->lw2[n*72 + k] = f2bf(fus_W2[i]);
  }
  if (tid < H) {
    S->lb2[tid] = fus_b2[tid];
    S->lgw[tid] = gate_W[tid];
  }
  if (tid < 64) {          // wave 0: prompt_zero, c1z, gz
    float u  = upd_b[tid];
    float mu = wave64_sum(u) * (1.0f/H);
    float d  = u - mu;
    float var= wave64_sum(d*d) * (1.0f/H);
    float p  = d * rsqrtf(var + LN_EPS) * ln_g[tid] + ln_b[tid];
    float acc = fus_b1[tid];
    #pragma unroll 8
    for (int k = 0; k < H; ++k)
      acc += __shfl(p, k, 64) * fus_W1[(H+k)*H + tid];
    S->lc1[tid] = acc;
    float gp = p * gate_W[H + tid];
    gp = wave64_sum(gp);
    if (tid == 0) S->lgz = gp + gate_b[0];
  }
  __syncthreads();

  int m = ln & 15, q = ln >> 4;
  float gz = S->lgz;
  int mb = blockIdx.x - NB_EDGE;

  for (int it = 0; it < TILES_PER_BLOCK; ++it) {
    int rowbase = (mb*TILES_PER_BLOCK + it)*64 + w*16;
    const float* arow = base + (size_t)(rowbase + m)*H;

    f32x4 a0 = *(const f32x4*)(arow + q*8);
    f32x4 a1 = *(const f32x4*)(arow + q*8 + 4);
    f32x4 a2 = *(const f32x4*)(arow + 32 + q*8);
    f32x4 a3 = *(const f32x4*)(arow + 32 + q*8 + 4);

    // gate logit: base . gate_W_top (reduce across q groups)
    float gp = 0.f;
    #pragma unroll
    for (int j = 0; j < 4; ++j) {
      gp += a0[j]*S->lgw[q*8+j]    + a1[j]*S->lgw[q*8+4+j];
      gp += a2[j]*S->lgw[32+q*8+j] + a3[j]*S->lgw[32+q*8+4+j];
    }
    gp += __shfl_xor(gp, 16, 64);
    gp += __shfl_xor(gp, 32, 64);
    float g = 1.0f / (1.0f + __expf(-(gp + gz)));
    if (q == 0) S->lg[w][m] = g;        // per-wave buffer, no barrier needed

    // A fragments (lane: row m, k = q*8+j)
    s16x8 A0, A1;
    #pragma unroll
    for (int j = 0; j < 4; ++j) {
      A0[j]   = (short)f2bf(a0[j]);
      A0[j+4] = (short)f2bf(a1[j]);
      A1[j]   = (short)f2bf(a2[j]);
      A1[j+4] = (short)f2bf(a3[j]);
    }

    // hidden = relu(base @ W1_top + c1z)   (c1z folded into C-init)
    f32x4 hacc[4];
    #pragma unroll
    for (int ct = 0; ct < 4; ++ct) {
      const s16x8 B0 = *(const s16x8*)&S->lw1[(ct*16 + m)*72 + q*8];
      const s16x8 B1 = *(const s16x8*)&S->lw1[(ct*16 + m)*72 + 32 + q*8];
      float c1v = S->lc1[ct*16 + m];
      f32x4 c = {c1v, c1v, c1v, c1v};
      c = __builtin_amdgcn_mfma_f32_16x16x32_bf16(A0, B0, c, 0, 0, 0);
      hacc[ct] = __builtin_amdgcn_mfma_f32_16x16x32_bf16(A1, B1, c, 0, 0, 0);
    }
    // D layout: col = ct*16+m, row = q*4+r  -> per-wave LDS round trip
    #pragma unroll
    for (int ct = 0; ct < 4; ++ct) {
      #pragma unroll
      for (int r = 0; r < 4; ++r) {
        float v = fmaxf(hacc[ct][r], 0.f);
        S->lhid[w][(q*4 + r)*72 + ct*16 + m] = f2bf(v);
      }
    }
    // same-wave write->read: compiler inserts lgkmcnt wait; no __syncthreads
    s16x8 HA0 = *(const s16x8*)&S->lhid[w][m*72 + q*8];
    s16x8 HA1 = *(const s16x8*)&S->lhid[w][m*72 + 32 + q*8];

    // fused = hidden @ W2 + fus_b2   (bias folded into C-init)
    f32x4 facc[4];
    #pragma unroll
    for (int ct = 0; ct < 4; ++ct) {
      const s16x8 B0 = *(const s16x8*)&S->lw2[(ct*16 + m)*72 + q*8];
      const s16x8 B1 = *(const s16x8*)&S->lw2[(ct*16 + m)*72 + 32 + q*8];
      float b2v = S->lb2[ct*16 + m];
      f32x4 c = {b2v, b2v, b2v, b2v};
      c = __builtin_amdgcn_mfma_f32_16x16x32_bf16(HA0, B0, c, 0, 0, 0);
      facc[ct] = __builtin_amdgcn_mfma_f32_16x16x32_bf16(HA1, B1, c, 0, 0, 0);
    }

    float gv[4];
    #pragma unroll
    for (int r = 0; r < 4; ++r) gv[r] = S->lg[w][q*4 + r];

    #pragma unroll
    for (int ct = 0; ct < 4; ++ct) {
      int col = ct*16 + m;
      #pragma unroll
      for (int r = 0; r < 4; ++r) {
        int row = rowbase + q*4 + r;
        float bval = base[(size_t)row*H + col];
        out[(size_t)row*H + col] = fmaf(gv[r], facc[ct][r] - bval, bval);
      }
    }
  }
}

// ---------------------------------------------------------------------------
// fixup: overwrite the <=E touched rows per sample with their true prompt.
// Wave w handles edges w, w+4, ... ; weights staged in LDS; no barriers after.
// ---------------------------------------------------------------------------
__global__ __launch_bounds__(256) void fixup_kernel(
    const float* __restrict__ base,
    const float* __restrict__ fus_W1, const float* __restrict__ fus_b1,
    const float* __restrict__ fus_W2, const float* __restrict__ fus_b2,
    const float* __restrict__ gate_W, const float* __restrict__ gate_b,
    const int* __restrict__ trows, const float* __restrict__ tprompt,
    float* __restrict__ out)
{
  __shared__ float W1s[2*H*H];   // 32 KB
  __shared__ float W2s[H*H];     // 16 KB
  int b = blockIdx.x, tid = threadIdx.x, w = tid >> 6, ln = tid & 63;
  for (int i = tid; i < 2*H*H; i += 256) W1s[i] = fus_W1[i];
  for (int i = tid; i < H*H;   i += 256) W2s[i] = fus_W2[i];
  __syncthreads();
  float gb = gate_b[0];
  #pragma unroll
  for (int i = 0; i < E/4; ++i) {
    int e = w + i*4;
    int r = trows[b*E + e];
    if (r < 0) continue;
    float bv = base[((size_t)b*R + r)*H + ln];
    float pv = tprompt[(b*E + e)*H + ln];
    float acc = fus_b1[ln];
    #pragma unroll 8
    for (int k = 0; k < H; ++k)
      acc += __shfl(bv, k, 64)*W1s[k*H + ln] + __shfl(pv, k, 64)*W1s[(H+k)*H + ln];
    float h = fmaxf(acc, 0.f);
    float f = fus_b2[ln];
    #pragma unroll 8
    for (int k = 0; k < H; ++k)
      f += __shfl(h, k, 64)*W2s[k*H + ln];
    float gp = bv*gate_W[ln] + pv*gate_W[H + ln];
    gp = wave64_sum(gp);
    float g = 1.0f/(1.0f + __expf(-(gp + gb)));
    out[((size_t)b*R + r)*H + ln] = fmaf(g, f - bv, bv);
  }
}

// ---------------------------------------------------------------------------
extern "C" void kernel_launch(void* const* d_in, const int* in_sizes, int n_in,
                              void* d_out, int out_size, void* d_ws, size_t ws_size,
                              hipStream_t stream)
{
  const int*   qrel   = (const int*)d_in[0];
  const int*   etyp   = (const int*)d_in[1];
  const float* base   = (const float*)d_in[2];
  const float* noise  = (const float*)d_in[3];
  const float* msg_W  = (const float*)d_in[4];
  const float* msg_b  = (const float*)d_in[5];
  const float* upd_W  = (const float*)d_in[6];
  const float* upd_b  = (const float*)d_in[7];
  const float* ln_g   = (const float*)d_in[8];
  const float* ln_b   = (const float*)d_in[9];
  const float* fus_W1 = (const float*)d_in[10];
  const float* fus_b1 = (const float*)d_in[11];
  const float* fus_W2 = (const float*)d_in[12];
  const float* fus_b2 = (const float*)d_in[13];
  const float* gate_W = (const float*)d_in[14];
  const float* gate_b = (const float*)d_in[15];
  float* out = (float*)d_out;

  char* ws = (char*)d_ws;
  float* tprompt = (float*)ws;                       // B*E*H f32
  int*   trows   = (int*)(ws + (size_t)B*E*H*4);     // B*E int

  fused_kernel<<<NB_EDGE + NB_MAIN, 256, 0, stream>>>(
      qrel, etyp, base, noise, msg_W, msg_b, upd_W, upd_b, ln_g, ln_b,
      fus_W1, fus_b1, fus_W2, fus_b2, gate_W, gate_b,
      trows, tprompt, out);
  fixup_kernel<<<B, 256, 0, stream>>>(base, fus_W1, fus_b1, fus_W2, fus_b2,
                                      gate_W, gate_b, trows, tprompt, out);
}